// Round 12
// baseline (3879.298 us; speedup 1.0000x reference)
//
#include <hip/hip_runtime.h>

#define TT 1024
#define BB 64
#define DD 512
#define HH 512
#define NG 4       // batch groups (16 batches each)
#define BPG 16
#define NS 32      // hidden slices (16 units each)
#define NTHR 256

typedef short s8v __attribute__((ext_vector_type(8)));
typedef float f4v __attribute__((ext_vector_type(4)));
typedef int i4v __attribute__((ext_vector_type(4)));

static __device__ __forceinline__ unsigned short f2bf(float f) {
  union { float f; unsigned int u; } v; v.f = f;
  unsigned int r = v.u + 0x7FFFu + ((v.u >> 16) & 1u);  // RNE
  return (unsigned short)(r >> 16);
}
static __device__ __forceinline__ i4v ld_b128_cohere(const void* p) {
  i4v r;
  asm volatile("global_load_dwordx4 %0, %1, off sc0 sc1"
               : "=v"(r) : "v"(p) : "memory");
  return r;
}
static __device__ __forceinline__ int ld_b32_cohere(const void* p) {
  int r;
  asm volatile("global_load_dword %0, %1, off sc0 sc1\n\t"
               "s_waitcnt vmcnt(0)"
               : "=v"(r) : "v"(p) : "memory");
  return r;
}
static __device__ __forceinline__ void st_b32_cohere(void* p, unsigned int v) {
  asm volatile("global_store_dword %0, %1, off sc0 sc1"
               :: "v"(p), "v"(v) : "memory");
}
static __device__ __forceinline__ void st_b64_cohere(void* p,
                                                     unsigned long long v) {
  asm volatile("global_store_dwordx2 %0, %1, off sc0 sc1"
               :: "v"(p), "v"(v) : "memory");
}
static __device__ __forceinline__ unsigned int cvtpk_bf16(float lo, float hi) {
  unsigned int r;
  asm("v_cvt_pk_bf16_f32 %0, %1, %2" : "=v"(r) : "v"(lo), "v"(hi));
  return r;
}

// Reset hint flags every launch (graph replays rerun this). Tags in hbuf need
// no reset: consumer requires tag == t-1 exactly; stale tags either never
// match or (replay edge) carry identical deterministic h values.
__global__ void __launch_bounds__(128, 1) qlstm_init(int* flags) {
  st_b32_cohere(flags + threadIdx.x, 0u);   // flags[NG][NS] = 128 ints
}

__global__ void __launch_bounds__(NTHR, 1) qlstm_main(
    const float* __restrict__ X,
    const float* __restrict__ Wf, const float* __restrict__ bfp,
    const float* __restrict__ Wi, const float* __restrict__ bip,
    const float* __restrict__ Wg, const float* __restrict__ bgp,
    const float* __restrict__ Wo, const float* __restrict__ bop,
    const float* __restrict__ phase,
    float* __restrict__ out, int* __restrict__ flags,
    unsigned long long* __restrict__ hbuf64) {
  __shared__ float zx[2][2][4][64][4];  // [par][khalf][tile][lane][i]
  __shared__ float zh[2][4][64][4];     // [khalf][tile][lane][i]
  const int tid   = threadIdx.x;
  const int wv    = tid >> 6;
  const int lane  = tid & 63;
  const int n     = lane & 15;
  const int kg    = lane >> 4;
  const int group = blockIdx.x & (NG - 1);
  const int slice = blockIdx.x >> 2;
  const int b0 = group * BPG;
  const int u0 = slice * 16;
  const bool isH = (wv >= 2);
  const int kh = wv & 1;   // K-half within role

  // Per-wave weights: 4 tiles x K=256 (layout identical to R9).
  const int wcol = u0 + (n & 7);
  s8v wreg[4][8];
#pragma unroll
  for (int T = 0; T < 4; ++T) {
    const float* Wsel = (T & 1) ? ((n < 8) ? Wg : Wo) : ((n < 8) ? Wf : Wi);
    const float* Wp = Wsel + (size_t)((isH ? 512 : 0) + kh * 256 + kg * 8) * HH
                    + wcol + (T >> 1) * 8;
#pragma unroll
    for (int kc = 0; kc < 8; ++kc)
#pragma unroll
      for (int j = 0; j < 8; ++j)
        wreg[T][kc][j] = (short)f2bf(Wp[(size_t)(kc * 32 + j) * HH]);
  }

  const int gb = tid >> 4, gu = tid & 15;
  const int uu = u0 + gu;
  const float bzf = bfp[uu] + phase[uu];
  const float bzi = bip[uu] + phase[uu];
  const float bzg = bgp[uu] + phase[uu];
  const float bzo = bop[uu] + phase[uu];
  float cst = 0.f;

  for (int p = tid; p < 2 * 4 * 64 * 4; p += NTHR) ((float*)zh)[p] = 0.f;
  float4 xv[16];
  s8v xf[8];
  if (!isH) {
    const float* Xr = X + ((size_t)0 * BB + b0 + n) * DD + kh * 256 + kg * 8;
#pragma unroll
    for (int kc = 0; kc < 8; ++kc) {
      xv[2 * kc]     = *(const float4*)(Xr + kc * 32);
      xv[2 * kc + 1] = *(const float4*)(Xr + kc * 32 + 4);
    }
#pragma unroll
    for (int kc = 0; kc < 8; ++kc) {
      union { s8v s; unsigned int d[4]; } af;
      af.d[0] = cvtpk_bf16(xv[2 * kc].x, xv[2 * kc].y);
      af.d[1] = cvtpk_bf16(xv[2 * kc].z, xv[2 * kc].w);
      af.d[2] = cvtpk_bf16(xv[2 * kc + 1].x, xv[2 * kc + 1].y);
      af.d[3] = cvtpk_bf16(xv[2 * kc + 1].z, xv[2 * kc + 1].w);
      xf[kc] = af.s;
    }
    f4v acc[4] = {{0.f,0.f,0.f,0.f},{0.f,0.f,0.f,0.f},{0.f,0.f,0.f,0.f},{0.f,0.f,0.f,0.f}};
#pragma unroll
    for (int kc = 0; kc < 8; ++kc)
#pragma unroll
      for (int T = 0; T < 4; ++T)
        acc[T] = __builtin_amdgcn_mfma_f32_16x16x32_bf16(xf[kc], wreg[T][kc], acc[T], 0, 0, 0);
#pragma unroll
    for (int T = 0; T < 4; ++T) *(f4v*)&zx[0][kh][T][lane][0] = acc[T];
    const float* X1 = X + ((size_t)1 * BB + b0 + n) * DD + kh * 256 + kg * 8;
#pragma unroll
    for (int kc = 0; kc < 8; ++kc) {
      xv[2 * kc]     = *(const float4*)(X1 + kc * 32);
      xv[2 * kc + 1] = *(const float4*)(X1 + kc * 32 + 4);
    }
  }

  int* myflag = flags + group * NS + slice;
  const int* pollp = flags + group * NS + (lane & 31);

  for (int t = 0; t < TT; ++t) {
    // ---------- P1: x-waves build zx(t+1); h-waves fetch h(t-1) + MFMA -----
    if (!isH) {
      if (t + 1 < TT) {
#pragma unroll
        for (int kc = 0; kc < 8; ++kc) {
          union { s8v s; unsigned int d[4]; } af;
          af.d[0] = cvtpk_bf16(xv[2 * kc].x, xv[2 * kc].y);
          af.d[1] = cvtpk_bf16(xv[2 * kc].z, xv[2 * kc].w);
          af.d[2] = cvtpk_bf16(xv[2 * kc + 1].x, xv[2 * kc + 1].y);
          af.d[3] = cvtpk_bf16(xv[2 * kc + 1].z, xv[2 * kc + 1].w);
          xf[kc] = af.s;
        }
        f4v acc[4] = {{0.f,0.f,0.f,0.f},{0.f,0.f,0.f,0.f},{0.f,0.f,0.f,0.f},{0.f,0.f,0.f,0.f}};
#pragma unroll
        for (int kc = 0; kc < 8; ++kc)
#pragma unroll
          for (int T = 0; T < 4; ++T)
            acc[T] = __builtin_amdgcn_mfma_f32_16x16x32_bf16(xf[kc], wreg[T][kc], acc[T], 0, 0, 0);
#pragma unroll
        for (int T = 0; T < 4; ++T)
          *(f4v*)&zx[(t + 1) & 1][kh][T][lane][0] = acc[T];
      }
    } else if (t > 0) {
      const int tm1 = t - 1;
      // tagged h(t-1): lane (row=b0+n, unit-pairs kh*128 + kc*16 + kg*4 +0..3)
      const unsigned long long* hb = hbuf64 + (size_t)(tm1 & 1) * BB * 256 +
                                     (size_t)(b0 + n) * 256 + kh * 128 + kg * 4;
      i4v hf[16];
      // attempt 0 is SPECULATIVE (no flag wait): for the pacing (late) WG the
      // data is already valid -> detect+load collapse to one round trip.
      for (int attempt = 0; ; ++attempt) {
#pragma unroll
        for (int kc = 0; kc < 8; ++kc) {
          hf[2 * kc]     = ld_b128_cohere(hb + kc * 16);
          hf[2 * kc + 1] = ld_b128_cohere(hb + kc * 16 + 2);
        }
        asm volatile("s_waitcnt vmcnt(0)" ::: "memory");   // rule-18 fence
        __builtin_amdgcn_sched_barrier(0);
        int bad = 0;
#pragma unroll
        for (int j = 0; j < 16; ++j)
          bad |= (hf[j][1] ^ tm1) | (hf[j][3] ^ tm1);
        if (__all(bad == 0)) break;
        if (attempt == 0) {
          for (;;) {   // hint poll: cheap 4B granularity
            const int v = ld_b32_cohere(pollp);
            if (__all(v >= t)) break;
            __builtin_amdgcn_s_sleep(1);
          }
        } else {
          __builtin_amdgcn_s_sleep(1);
        }
      }
      f4v acc[4] = {{0.f,0.f,0.f,0.f},{0.f,0.f,0.f,0.f},{0.f,0.f,0.f,0.f},{0.f,0.f,0.f,0.f}};
#pragma unroll
      for (int kc = 0; kc < 8; ++kc) {
        union { i4v i; s8v s; } af;
        af.i[0] = hf[2 * kc][0];
        af.i[1] = hf[2 * kc][2];
        af.i[2] = hf[2 * kc + 1][0];
        af.i[3] = hf[2 * kc + 1][2];
#pragma unroll
        for (int T = 0; T < 4; ++T)
          acc[T] = __builtin_amdgcn_mfma_f32_16x16x32_bf16(af.s, wreg[T][kc], acc[T], 0, 0, 0);
      }
#pragma unroll
      for (int T = 0; T < 4; ++T) *(f4v*)&zh[kh][T][lane][0] = acc[T];
    }
    __syncthreads();                                    // bar1

    // ---------- gates on ALL 256 threads (1 unit each; layout = R9) --------
    const int par = t & 1;
    const int Lf  = (gb >> 2) * 16 + (gu & 7);
    const int T0  = (gu >> 3) * 2;
    const int ci  = gb & 3;
    const float zfv = zx[par][0][T0][Lf][ci]     + zx[par][1][T0][Lf][ci]
                    + zh[0][T0][Lf][ci]          + zh[1][T0][Lf][ci] + bzf;
    const float ziv = zx[par][0][T0][Lf+8][ci]   + zx[par][1][T0][Lf+8][ci]
                    + zh[0][T0][Lf+8][ci]        + zh[1][T0][Lf+8][ci] + bzi;
    const float zgv = zx[par][0][T0+1][Lf][ci]   + zx[par][1][T0+1][Lf][ci]
                    + zh[0][T0+1][Lf][ci]        + zh[1][T0+1][Lf][ci] + bzg;
    const float zov = zx[par][0][T0+1][Lf+8][ci] + zx[par][1][T0+1][Lf+8][ci]
                    + zh[0][T0+1][Lf+8][ci]      + zh[1][T0+1][Lf+8][ci] + bzo;
    const float fg = 1.f / (1.f + __expf(-zfv));
    const float ig = 1.f / (1.f + __expf(-ziv));
    const float gg = 1.f - 2.f / (__expf(2.f * zgv) + 1.f);
    const float og = 1.f / (1.f + __expf(-zov));
    cst = fg * cst + ig * gg;
    const float hv = og * (1.f - 2.f / (__expf(2.f * cst) + 1.f));

    // ---------- publish tagged h: fire-and-forget; flag = immediate hint ----
    const float hn = __shfl_down(hv, 1);
    if (!(gu & 1)) {
      const unsigned long long d =
          ((unsigned long long)(unsigned)t << 32) |
          (unsigned long long)cvtpk_bf16(hv, hn);
      st_b64_cohere(hbuf64 + (size_t)par * BB * 256 +
                        (size_t)(b0 + gb) * 256 + (uu >> 1), d);
    }
    if (tid == 0) st_b32_cohere(myflag, (unsigned int)(t + 1));

    // out stores + x prefetch issue; bar2's implicit drain overlaps with the
    // consumers' detection (off the inter-WG critical path).
    out[(size_t)t * BB * HH + (size_t)(b0 + gb) * HH + uu] = hv;
    if (t == TT - 1) {
      out[(size_t)TT * BB * HH + (size_t)(b0 + gb) * HH + uu] = hv;           // hx
      out[(size_t)TT * BB * HH + BB * HH + (size_t)(b0 + gb) * HH + uu] = cst; // cx
    }
    if (!isH && t + 2 < TT) {
      const float* Xr = X + ((size_t)(t + 2) * BB + b0 + n) * DD + kh * 256 + kg * 8;
#pragma unroll
      for (int kc = 0; kc < 8; ++kc) {
        xv[2 * kc]     = *(const float4*)(Xr + kc * 32);
        xv[2 * kc + 1] = *(const float4*)(Xr + kc * 32 + 4);
      }
    }
    __syncthreads();                                    // bar2
  }
}

extern "C" void kernel_launch(void* const* d_in, const int* in_sizes, int n_in,
                              void* d_out, int out_size, void* d_ws,
                              size_t ws_size, hipStream_t stream) {
  const float* X   = (const float*)d_in[0];
  const float* Wf  = (const float*)d_in[1];
  const float* bfp = (const float*)d_in[2];
  const float* Wi  = (const float*)d_in[3];
  const float* bip = (const float*)d_in[4];
  const float* Wg  = (const float*)d_in[5];
  const float* bgp = (const float*)d_in[6];
  const float* Wo  = (const float*)d_in[7];
  const float* bop = (const float*)d_in[8];
  const float* ph  = (const float*)d_in[9];
  float* out = (float*)d_out;

  // ws: [0, 512B) hint flags[NG][NS]; [4KB, 4KB+256KB) tagged-h double buffer
  int* flags = (int*)d_ws;
  unsigned long long* hbuf64 = (unsigned long long*)((char*)d_ws + 4096);

  qlstm_init<<<1, 128, 0, stream>>>(flags);
  qlstm_main<<<NG * NS, NTHR, 0, stream>>>(X, Wf, bfp, Wi, bip, Wg, bgp, Wo,
                                           bop, ph, out, flags, hbuf64);
}

// Round 13
// 3671.278 us; speedup vs baseline: 1.0567x; 1.0567x over previous
//
#include <hip/hip_runtime.h>

#define TT 1024
#define BB 64
#define DD 512
#define HH 512
#define NG 4       // batch groups (16 batches each)
#define BPG 16
#define NS 32      // hidden slices (16 units each)
#define NTHR 256

typedef short s8v __attribute__((ext_vector_type(8)));
typedef float f4v __attribute__((ext_vector_type(4)));
typedef int i4v __attribute__((ext_vector_type(4)));

static __device__ __forceinline__ unsigned short f2bf(float f) {
  union { float f; unsigned int u; } v; v.f = f;
  unsigned int r = v.u + 0x7FFFu + ((v.u >> 16) & 1u);  // RNE
  return (unsigned short)(r >> 16);
}
static __device__ __forceinline__ i4v ld_b128_cohere(const void* p) {
  i4v r;
  asm volatile("global_load_dwordx4 %0, %1, off sc0 sc1"
               : "=v"(r) : "v"(p) : "memory");
  return r;
}
static __device__ __forceinline__ int ld_b32_cohere(const void* p) {
  int r;
  asm volatile("global_load_dword %0, %1, off sc0 sc1\n\t"
               "s_waitcnt vmcnt(0)"
               : "=v"(r) : "v"(p) : "memory");
  return r;
}
static __device__ __forceinline__ void st_b32_cohere(void* p, unsigned int v) {
  asm volatile("global_store_dword %0, %1, off sc0 sc1"
               :: "v"(p), "v"(v) : "memory");
}
static __device__ __forceinline__ void st_b64_cohere(void* p,
                                                     unsigned long long v) {
  asm volatile("global_store_dwordx2 %0, %1, off sc0 sc1"
               :: "v"(p), "v"(v) : "memory");
}
static __device__ __forceinline__ unsigned int cvtpk_bf16(float lo, float hi) {
  unsigned int r;
  asm("v_cvt_pk_bf16_f32 %0, %1, %2" : "=v"(r) : "v"(lo), "v"(hi));
  return r;
}

// Reset hint flags every launch (graph replays rerun this). Tags in hbuf need
// no reset: consumer requires tag == t-1 exactly; stale tags either never
// match or (replay edge) carry identical deterministic h values.
__global__ void __launch_bounds__(128, 1) qlstm_init(int* flags) {
  st_b32_cohere(flags + threadIdx.x, 0u);   // flags[NG][NS] = 128 ints
}

__global__ void __launch_bounds__(NTHR, 1) qlstm_main(
    const float* __restrict__ X,
    const float* __restrict__ Wf, const float* __restrict__ bfp,
    const float* __restrict__ Wi, const float* __restrict__ bip,
    const float* __restrict__ Wg, const float* __restrict__ bgp,
    const float* __restrict__ Wo, const float* __restrict__ bop,
    const float* __restrict__ phase,
    float* __restrict__ out, int* __restrict__ flags,
    unsigned long long* __restrict__ hbuf64) {
  __shared__ float zx[2][2][4][64][4];  // [par][khalf][tile][lane][i]
  __shared__ float zh[2][4][64][4];     // [khalf][tile][lane][i]
  const int tid   = threadIdx.x;
  const int wv    = tid >> 6;
  const int lane  = tid & 63;
  const int n     = lane & 15;
  const int kg    = lane >> 4;
  const int group = blockIdx.x & (NG - 1);
  const int slice = blockIdx.x >> 2;
  const int b0 = group * BPG;
  const int u0 = slice * 16;
  const bool isH = (wv >= 2);
  const int kh = wv & 1;   // K-half within role

  // Per-wave weights: 4 tiles x K=256 (layout identical to R9).
  const int wcol = u0 + (n & 7);
  s8v wreg[4][8];
#pragma unroll
  for (int T = 0; T < 4; ++T) {
    const float* Wsel = (T & 1) ? ((n < 8) ? Wg : Wo) : ((n < 8) ? Wf : Wi);
    const float* Wp = Wsel + (size_t)((isH ? 512 : 0) + kh * 256 + kg * 8) * HH
                    + wcol + (T >> 1) * 8;
#pragma unroll
    for (int kc = 0; kc < 8; ++kc)
#pragma unroll
      for (int j = 0; j < 8; ++j)
        wreg[T][kc][j] = (short)f2bf(Wp[(size_t)(kc * 32 + j) * HH]);
  }

  const int gb = tid >> 4, gu = tid & 15;
  const int uu = u0 + gu;
  const float bzf = bfp[uu] + phase[uu];
  const float bzi = bip[uu] + phase[uu];
  const float bzg = bgp[uu] + phase[uu];
  const float bzo = bop[uu] + phase[uu];
  float cst = 0.f;

  for (int p = tid; p < 2 * 4 * 64 * 4; p += NTHR) ((float*)zh)[p] = 0.f;
  float4 xv[16];
  s8v xf[8];
  if (!isH) {
    const float* Xr = X + ((size_t)0 * BB + b0 + n) * DD + kh * 256 + kg * 8;
#pragma unroll
    for (int kc = 0; kc < 8; ++kc) {
      xv[2 * kc]     = *(const float4*)(Xr + kc * 32);
      xv[2 * kc + 1] = *(const float4*)(Xr + kc * 32 + 4);
    }
#pragma unroll
    for (int kc = 0; kc < 8; ++kc) {
      union { s8v s; unsigned int d[4]; } af;
      af.d[0] = cvtpk_bf16(xv[2 * kc].x, xv[2 * kc].y);
      af.d[1] = cvtpk_bf16(xv[2 * kc].z, xv[2 * kc].w);
      af.d[2] = cvtpk_bf16(xv[2 * kc + 1].x, xv[2 * kc + 1].y);
      af.d[3] = cvtpk_bf16(xv[2 * kc + 1].z, xv[2 * kc + 1].w);
      xf[kc] = af.s;
    }
    f4v acc[4] = {{0.f,0.f,0.f,0.f},{0.f,0.f,0.f,0.f},{0.f,0.f,0.f,0.f},{0.f,0.f,0.f,0.f}};
#pragma unroll
    for (int kc = 0; kc < 8; ++kc)
#pragma unroll
      for (int T = 0; T < 4; ++T)
        acc[T] = __builtin_amdgcn_mfma_f32_16x16x32_bf16(xf[kc], wreg[T][kc], acc[T], 0, 0, 0);
#pragma unroll
    for (int T = 0; T < 4; ++T) *(f4v*)&zx[0][kh][T][lane][0] = acc[T];
    const float* X1 = X + ((size_t)1 * BB + b0 + n) * DD + kh * 256 + kg * 8;
#pragma unroll
    for (int kc = 0; kc < 8; ++kc) {
      xv[2 * kc]     = *(const float4*)(X1 + kc * 32);
      xv[2 * kc + 1] = *(const float4*)(X1 + kc * 32 + 4);
    }
  }

  int* myflag = flags + group * NS + slice;
  const int* pollp = flags + group * NS + (lane & 31);

  for (int t = 0; t < TT; ++t) {
    // ---------- P1: x-waves build zx(t+1); h-waves fetch h(t-1) + MFMA -----
    if (!isH) {
      if (t + 1 < TT) {
#pragma unroll
        for (int kc = 0; kc < 8; ++kc) {
          union { s8v s; unsigned int d[4]; } af;
          af.d[0] = cvtpk_bf16(xv[2 * kc].x, xv[2 * kc].y);
          af.d[1] = cvtpk_bf16(xv[2 * kc].z, xv[2 * kc].w);
          af.d[2] = cvtpk_bf16(xv[2 * kc + 1].x, xv[2 * kc + 1].y);
          af.d[3] = cvtpk_bf16(xv[2 * kc + 1].z, xv[2 * kc + 1].w);
          xf[kc] = af.s;
        }
        f4v acc[4] = {{0.f,0.f,0.f,0.f},{0.f,0.f,0.f,0.f},{0.f,0.f,0.f,0.f},{0.f,0.f,0.f,0.f}};
#pragma unroll
        for (int kc = 0; kc < 8; ++kc)
#pragma unroll
          for (int T = 0; T < 4; ++T)
            acc[T] = __builtin_amdgcn_mfma_f32_16x16x32_bf16(xf[kc], wreg[T][kc], acc[T], 0, 0, 0);
#pragma unroll
        for (int T = 0; T < 4; ++T)
          *(f4v*)&zx[(t + 1) & 1][kh][T][lane][0] = acc[T];
      }
    } else if (t > 0) {
      const int tm1 = t - 1;
      // mandatory flag poll FIRST (cheap 4B; flag was issued right after the
      // producers' data stores, so by detect time data is in L3)
      for (;;) {
        const int v = ld_b32_cohere(pollp);
        if (__all(v >= t)) break;
        __builtin_amdgcn_s_sleep(1);
      }
      // tagged h(t-1): lane (row=b0+n, u64s kh*128 + kc*16 + kg*4 + {0..3})
      const unsigned long long* hb = hbuf64 + (size_t)(tm1 & 1) * BB * 256 +
                                     (size_t)(b0 + n) * 256 + kh * 128 + kg * 4;
      i4v hf[16];
      for (;;) {   // single load + tag verify; retry only if flag beat a store
#pragma unroll
        for (int kc = 0; kc < 8; ++kc) {
          hf[2 * kc]     = ld_b128_cohere(hb + kc * 16);
          hf[2 * kc + 1] = ld_b128_cohere(hb + kc * 16 + 2);
        }
        asm volatile("s_waitcnt vmcnt(0)" ::: "memory");   // rule-18 fence
        __builtin_amdgcn_sched_barrier(0);
        int bad = 0;
#pragma unroll
        for (int j = 0; j < 16; ++j)
          bad |= (hf[j][1] ^ tm1) | (hf[j][3] ^ tm1);
        if (__all(bad == 0)) break;
        __builtin_amdgcn_s_sleep(1);
      }
      f4v acc[4] = {{0.f,0.f,0.f,0.f},{0.f,0.f,0.f,0.f},{0.f,0.f,0.f,0.f},{0.f,0.f,0.f,0.f}};
#pragma unroll
      for (int kc = 0; kc < 8; ++kc) {
        union { i4v i; s8v s; } af;
        af.i[0] = hf[2 * kc][0];
        af.i[1] = hf[2 * kc][2];
        af.i[2] = hf[2 * kc + 1][0];
        af.i[3] = hf[2 * kc + 1][2];
#pragma unroll
        for (int T = 0; T < 4; ++T)
          acc[T] = __builtin_amdgcn_mfma_f32_16x16x32_bf16(af.s, wreg[T][kc], acc[T], 0, 0, 0);
      }
#pragma unroll
      for (int T = 0; T < 4; ++T) *(f4v*)&zh[kh][T][lane][0] = acc[T];
    }
    __syncthreads();                                    // bar1

    // ---------- gates on ALL 256 threads (1 unit each; layout = R9) --------
    const int par = t & 1;
    const int Lf  = (gb >> 2) * 16 + (gu & 7);
    const int T0  = (gu >> 3) * 2;
    const int ci  = gb & 3;
    const float zfv = zx[par][0][T0][Lf][ci]     + zx[par][1][T0][Lf][ci]
                    + zh[0][T0][Lf][ci]          + zh[1][T0][Lf][ci] + bzf;
    const float ziv = zx[par][0][T0][Lf+8][ci]   + zx[par][1][T0][Lf+8][ci]
                    + zh[0][T0][Lf+8][ci]        + zh[1][T0][Lf+8][ci] + bzi;
    const float zgv = zx[par][0][T0+1][Lf][ci]   + zx[par][1][T0+1][Lf][ci]
                    + zh[0][T0+1][Lf][ci]        + zh[1][T0+1][Lf][ci] + bzg;
    const float zov = zx[par][0][T0+1][Lf+8][ci] + zx[par][1][T0+1][Lf+8][ci]
                    + zh[0][T0+1][Lf+8][ci]      + zh[1][T0+1][Lf+8][ci] + bzo;
    const float fg = 1.f / (1.f + __expf(-zfv));
    const float ig = 1.f / (1.f + __expf(-ziv));
    const float gg = 1.f - 2.f / (__expf(2.f * zgv) + 1.f);
    const float og = 1.f / (1.f + __expf(-zov));
    cst = fg * cst + ig * gg;
    const float hv = og * (1.f - 2.f / (__expf(2.f * cst) + 1.f));

    // ---------- publish tagged h, then flag IMMEDIATELY (no drain between:
    // tags carry validity; consumer verifies). bar2's drain is now after the
    // flag -> overlapped with consumer detection, off the inter-WG path. ----
    const float hn = __shfl_down(hv, 1);
    if (!(gu & 1)) {
      const unsigned long long d =
          ((unsigned long long)(unsigned)t << 32) |
          (unsigned long long)cvtpk_bf16(hv, hn);
      st_b64_cohere(hbuf64 + (size_t)par * BB * 256 +
                        (size_t)(b0 + gb) * 256 + (uu >> 1), d);
    }
    if (tid == 0) st_b32_cohere(myflag, (unsigned int)(t + 1));

    // out stores after flag (off critical path)
    out[(size_t)t * BB * HH + (size_t)(b0 + gb) * HH + uu] = hv;
    if (t == TT - 1) {
      out[(size_t)TT * BB * HH + (size_t)(b0 + gb) * HH + uu] = hv;           // hx
      out[(size_t)TT * BB * HH + BB * HH + (size_t)(b0 + gb) * HH + uu] = cst; // cx
    }
    if (!isH && t + 2 < TT) {
      const float* Xr = X + ((size_t)(t + 2) * BB + b0 + n) * DD + kh * 256 + kg * 8;
#pragma unroll
      for (int kc = 0; kc < 8; ++kc) {
        xv[2 * kc]     = *(const float4*)(Xr + kc * 32);
        xv[2 * kc + 1] = *(const float4*)(Xr + kc * 32 + 4);
      }
    }
    __syncthreads();                                    // bar2
  }
}

extern "C" void kernel_launch(void* const* d_in, const int* in_sizes, int n_in,
                              void* d_out, int out_size, void* d_ws,
                              size_t ws_size, hipStream_t stream) {
  const float* X   = (const float*)d_in[0];
  const float* Wf  = (const float*)d_in[1];
  const float* bfp = (const float*)d_in[2];
  const float* Wi  = (const float*)d_in[3];
  const float* bip = (const float*)d_in[4];
  const float* Wg  = (const float*)d_in[5];
  const float* bgp = (const float*)d_in[6];
  const float* Wo  = (const float*)d_in[7];
  const float* bop = (const float*)d_in[8];
  const float* ph  = (const float*)d_in[9];
  float* out = (float*)d_out;

  // ws: [0, 512B) flags[NG][NS]; [4KB, 4KB+256KB) tagged-h double buffer
  int* flags = (int*)d_ws;
  unsigned long long* hbuf64 = (unsigned long long*)((char*)d_ws + 4096);

  qlstm_init<<<1, 128, 0, stream>>>(flags);
  qlstm_main<<<NG * NS, NTHR, 0, stream>>>(X, Wf, bfp, Wi, bip, Wg, bgp, Wo,
                                           bop, ph, out, flags, hbuf64);
}

// Round 14
// 2920.859 us; speedup vs baseline: 1.3281x; 1.2569x over previous
//
#include <hip/hip_runtime.h>

#define TT 1024
#define BB 64
#define DD 512
#define HH 512
#define NG 4       // batch groups (16 batches each)
#define BPG 16
#define NS 32      // hidden slices (16 units each)
#define NTHR 256

typedef short s8v __attribute__((ext_vector_type(8)));
typedef float f4v __attribute__((ext_vector_type(4)));
typedef int i4v __attribute__((ext_vector_type(4)));

// raw barrier: LDS visibility only (lgkm), does NOT drain vmcnt -> global
// loads stay in flight across it (unlike __syncthreads' vmcnt(0) drain).
#define LGKM_BAR()                                          \
  do {                                                      \
    asm volatile("s_waitcnt lgkmcnt(0)" ::: "memory");      \
    __builtin_amdgcn_sched_barrier(0);                      \
    __builtin_amdgcn_s_barrier();                           \
    __builtin_amdgcn_sched_barrier(0);                      \
  } while (0)

static __device__ __forceinline__ unsigned short f2bf(float f) {
  union { float f; unsigned int u; } v; v.f = f;
  unsigned int r = v.u + 0x7FFFu + ((v.u >> 16) & 1u);  // RNE
  return (unsigned short)(r >> 16);
}
static __device__ __forceinline__ i4v ld_b128_cohere(const void* p) {
  i4v r;
  asm volatile("global_load_dwordx4 %0, %1, off sc0 sc1"
               : "=v"(r) : "v"(p) : "memory");
  return r;
}
static __device__ __forceinline__ int ld_b32_cohere(const void* p) {
  int r;
  asm volatile("global_load_dword %0, %1, off sc0 sc1\n\t"
               "s_waitcnt vmcnt(0)"
               : "=v"(r) : "v"(p) : "memory");
  return r;
}
static __device__ __forceinline__ void st_b32_cohere(void* p, unsigned int v) {
  asm volatile("global_store_dword %0, %1, off sc0 sc1"
               :: "v"(p), "v"(v) : "memory");
}
static __device__ __forceinline__ unsigned int cvtpk_bf16(float lo, float hi) {
  unsigned int r;
  asm("v_cvt_pk_bf16_f32 %0, %1, %2" : "=v"(r) : "v"(lo), "v"(hi));
  return r;
}

// Reset flags every launch (graph replays rerun this).
__global__ void __launch_bounds__(128, 1) qlstm_init(int* flags) {
  st_b32_cohere(flags + threadIdx.x, 0u);   // flags[NG][NS] = 128 ints
}

__global__ void __launch_bounds__(NTHR, 1) qlstm_main(
    const float* __restrict__ X,
    const float* __restrict__ Wf, const float* __restrict__ bfp,
    const float* __restrict__ Wi, const float* __restrict__ bip,
    const float* __restrict__ Wg, const float* __restrict__ bgp,
    const float* __restrict__ Wo, const float* __restrict__ bop,
    const float* __restrict__ phase,
    float* __restrict__ out, int* __restrict__ flags,
    unsigned short* __restrict__ hbuf) {
  __shared__ float zx[2][2][4][64][4];  // [par][khalf][tile][lane][i]
  __shared__ float zh[2][4][64][4];     // [khalf][tile][lane][i]
  const int tid   = threadIdx.x;
  const int wv    = tid >> 6;
  const int lane  = tid & 63;
  const int n     = lane & 15;
  const int kg    = lane >> 4;
  const int group = blockIdx.x & (NG - 1);
  const int slice = blockIdx.x >> 2;
  const int b0 = group * BPG;
  const int u0 = slice * 16;
  const bool isH = (wv >= 2);
  const int kh = wv & 1;   // K-half within role

  // Per-wave weights: 4 tiles x K=256 (layout identical to R9).
  const int wcol = u0 + (n & 7);
  s8v wreg[4][8];
#pragma unroll
  for (int T = 0; T < 4; ++T) {
    const float* Wsel = (T & 1) ? ((n < 8) ? Wg : Wo) : ((n < 8) ? Wf : Wi);
    const float* Wp = Wsel + (size_t)((isH ? 512 : 0) + kh * 256 + kg * 8) * HH
                    + wcol + (T >> 1) * 8;
#pragma unroll
    for (int kc = 0; kc < 8; ++kc)
#pragma unroll
      for (int j = 0; j < 8; ++j)
        wreg[T][kc][j] = (short)f2bf(Wp[(size_t)(kc * 32 + j) * HH]);
  }

  const int gb = tid >> 4, gu = tid & 15;
  const int uu = u0 + gu;
  const float bzf = bfp[uu] + phase[uu];
  const float bzi = bip[uu] + phase[uu];
  const float bzg = bgp[uu] + phase[uu];
  const float bzo = bop[uu] + phase[uu];
  float cst = 0.f;

  // prologue: zero zh (h(-1)=0); x-waves compute zx(0), issue LD(1)
  for (int p = tid; p < 2 * 4 * 64 * 4; p += NTHR) ((float*)zh)[p] = 0.f;
  float4 xv[16];
  s8v xf[8];
  if (!isH) {
    const float* Xr = X + ((size_t)0 * BB + b0 + n) * DD + kh * 256 + kg * 8;
#pragma unroll
    for (int kc = 0; kc < 8; ++kc) {
      xv[2 * kc]     = *(const float4*)(Xr + kc * 32);
      xv[2 * kc + 1] = *(const float4*)(Xr + kc * 32 + 4);
    }
#pragma unroll
    for (int kc = 0; kc < 8; ++kc) {
      union { s8v s; unsigned int d[4]; } af;
      af.d[0] = cvtpk_bf16(xv[2 * kc].x, xv[2 * kc].y);
      af.d[1] = cvtpk_bf16(xv[2 * kc].z, xv[2 * kc].w);
      af.d[2] = cvtpk_bf16(xv[2 * kc + 1].x, xv[2 * kc + 1].y);
      af.d[3] = cvtpk_bf16(xv[2 * kc + 1].z, xv[2 * kc + 1].w);
      xf[kc] = af.s;
    }
    f4v acc[4] = {{0.f,0.f,0.f,0.f},{0.f,0.f,0.f,0.f},{0.f,0.f,0.f,0.f},{0.f,0.f,0.f,0.f}};
#pragma unroll
    for (int kc = 0; kc < 8; ++kc)
#pragma unroll
      for (int T = 0; T < 4; ++T)
        acc[T] = __builtin_amdgcn_mfma_f32_16x16x32_bf16(xf[kc], wreg[T][kc], acc[T], 0, 0, 0);
#pragma unroll
    for (int T = 0; T < 4; ++T) *(f4v*)&zx[0][kh][T][lane][0] = acc[T];
    const float* X1 = X + ((size_t)1 * BB + b0 + n) * DD + kh * 256 + kg * 8;
#pragma unroll
    for (int kc = 0; kc < 8; ++kc) {
      xv[2 * kc]     = *(const float4*)(X1 + kc * 32);
      xv[2 * kc + 1] = *(const float4*)(X1 + kc * 32 + 4);
    }
  }

  int* myflag = flags + group * NS + slice;
  const int* pollp = flags + group * NS + (lane & 31);

  for (int t = 0; t < TT; ++t) {
    // ---------- P1: x-waves build zx(t+1); h-waves poll+load+MFMA zh(t) ----
    if (!isH) {
      if (t + 1 < TT) {
        // cvt xv (loads issued last step -> a full step of flight time)
#pragma unroll
        for (int kc = 0; kc < 8; ++kc) {
          union { s8v s; unsigned int d[4]; } af;
          af.d[0] = cvtpk_bf16(xv[2 * kc].x, xv[2 * kc].y);
          af.d[1] = cvtpk_bf16(xv[2 * kc].z, xv[2 * kc].w);
          af.d[2] = cvtpk_bf16(xv[2 * kc + 1].x, xv[2 * kc + 1].y);
          af.d[3] = cvtpk_bf16(xv[2 * kc + 1].z, xv[2 * kc + 1].w);
          xf[kc] = af.s;
        }
        f4v acc[4] = {{0.f,0.f,0.f,0.f},{0.f,0.f,0.f,0.f},{0.f,0.f,0.f,0.f},{0.f,0.f,0.f,0.f}};
#pragma unroll
        for (int kc = 0; kc < 8; ++kc)
#pragma unroll
          for (int T = 0; T < 4; ++T)
            acc[T] = __builtin_amdgcn_mfma_f32_16x16x32_bf16(xf[kc], wreg[T][kc], acc[T], 0, 0, 0);
#pragma unroll
        for (int T = 0; T < 4; ++T)
          *(f4v*)&zx[(t + 1) & 1][kh][T][lane][0] = acc[T];
      }
    } else if (t > 0) {
      for (;;) {
        const int v = ld_b32_cohere(pollp);
        if (__all(v >= t)) break;
        __builtin_amdgcn_s_sleep(1);
      }
      // h(t-1) direct global->A-frag: lane (row=b0+n, k=kh*256+kc*32+kg*8+j)
      const unsigned short* hb = hbuf + (size_t)((t - 1) & 1) * BB * HH +
                                 (size_t)(b0 + n) * HH + kh * 256 + kg * 8;
      i4v hf[8];
#pragma unroll
      for (int kc = 0; kc < 8; ++kc) hf[kc] = ld_b128_cohere(hb + kc * 32);
      asm volatile("s_waitcnt vmcnt(0)" ::: "memory");   // rule-18 fence
      __builtin_amdgcn_sched_barrier(0);
      f4v acc[4] = {{0.f,0.f,0.f,0.f},{0.f,0.f,0.f,0.f},{0.f,0.f,0.f,0.f},{0.f,0.f,0.f,0.f}};
#pragma unroll
      for (int kc = 0; kc < 8; ++kc) {
        union { i4v i; s8v s; } af; af.i = hf[kc];
#pragma unroll
        for (int T = 0; T < 4; ++T)
          acc[T] = __builtin_amdgcn_mfma_f32_16x16x32_bf16(af.s, wreg[T][kc], acc[T], 0, 0, 0);
      }
#pragma unroll
      for (int T = 0; T < 4; ++T) *(f4v*)&zh[kh][T][lane][0] = acc[T];
    }
    LGKM_BAR();                                         // bar1 (raw)

    // ---------- gates on ALL 256 threads (1 unit each; layout = R9) --------
    const int par = t & 1;
    const int Lf  = (gb >> 2) * 16 + (gu & 7);
    const int T0  = (gu >> 3) * 2;
    const int ci  = gb & 3;
    const float zfv = zx[par][0][T0][Lf][ci]     + zx[par][1][T0][Lf][ci]
                    + zh[0][T0][Lf][ci]          + zh[1][T0][Lf][ci] + bzf;
    const float ziv = zx[par][0][T0][Lf+8][ci]   + zx[par][1][T0][Lf+8][ci]
                    + zh[0][T0][Lf+8][ci]        + zh[1][T0][Lf+8][ci] + bzi;
    const float zgv = zx[par][0][T0+1][Lf][ci]   + zx[par][1][T0+1][Lf][ci]
                    + zh[0][T0+1][Lf][ci]        + zh[1][T0+1][Lf][ci] + bzg;
    const float zov = zx[par][0][T0+1][Lf+8][ci] + zx[par][1][T0+1][Lf+8][ci]
                    + zh[0][T0+1][Lf+8][ci]      + zh[1][T0+1][Lf+8][ci] + bzo;
    const float fg = 1.f / (1.f + __expf(-zfv));
    const float ig = 1.f / (1.f + __expf(-ziv));
    const float gg = 1.f - 2.f / (__expf(2.f * zgv) + 1.f);
    const float og = 1.f / (1.f + __expf(-zov));
    cst = fg * cst + ig * gg;
    const float hv = og * (1.f - 2.f / (__expf(2.f * cst) + 1.f));

    // ---------- publish h; x-waves then issue LD(t+2); counted drain -------
    const float hn = __shfl_down(hv, 1);
    if (!(gu & 1))
      st_b32_cohere(hbuf + (size_t)par * BB * HH + (size_t)(b0 + gb) * HH + uu,
                    cvtpk_bf16(hv, hn));                 // 1 store (oldest)
    if (!isH && t + 2 < TT) {
      const float* Xr = X + ((size_t)(t + 2) * BB + b0 + n) * DD + kh * 256 + kg * 8;
#pragma unroll
      for (int kc = 0; kc < 8; ++kc) {                   // 16 b128 loads
        xv[2 * kc]     = *(const float4*)(Xr + kc * 32);
        xv[2 * kc + 1] = *(const float4*)(Xr + kc * 32 + 4);
      }
      // wait for the publish store ONLY (oldest of 17): loads stay in flight
      asm volatile("s_waitcnt vmcnt(16)" ::: "memory");
    } else {
      asm volatile("s_waitcnt vmcnt(0)" ::: "memory");   // h-waves + tail
    }
    __builtin_amdgcn_sched_barrier(0);
    __builtin_amdgcn_s_barrier();   // ALL waves' publish stores acked (race fix)
    __builtin_amdgcn_sched_barrier(0);
    if (tid == 0) st_b32_cohere(myflag, (unsigned int)(t + 1));

    // out stores after flag; never drained by a barrier (acked next step)
    out[(size_t)t * BB * HH + (size_t)(b0 + gb) * HH + uu] = hv;
    if (t == TT - 1) {
      out[(size_t)TT * BB * HH + (size_t)(b0 + gb) * HH + uu] = hv;          // hx
      out[(size_t)TT * BB * HH + BB * HH + (size_t)(b0 + gb) * HH + uu] = cst; // cx
    }
    LGKM_BAR();                                         // bar2 (raw)
  }
}

extern "C" void kernel_launch(void* const* d_in, const int* in_sizes, int n_in,
                              void* d_out, int out_size, void* d_ws,
                              size_t ws_size, hipStream_t stream) {
  const float* X   = (const float*)d_in[0];
  const float* Wf  = (const float*)d_in[1];
  const float* bfp = (const float*)d_in[2];
  const float* Wi  = (const float*)d_in[3];
  const float* bip = (const float*)d_in[4];
  const float* Wg  = (const float*)d_in[5];
  const float* bgp = (const float*)d_in[6];
  const float* Wo  = (const float*)d_in[7];
  const float* bop = (const float*)d_in[8];
  const float* ph  = (const float*)d_in[9];
  float* out = (float*)d_out;

  // ws: [0, 512B) flags[NG][NS]; [4KB, 4KB+128KB) bf16 h double-buffer
  int* flags = (int*)d_ws;
  unsigned short* hbuf = (unsigned short*)((char*)d_ws + 4096);

  qlstm_init<<<1, 128, 0, stream>>>(flags);
  qlstm_main<<<NG * NS, NTHR, 0, stream>>>(X, Wf, bfp, Wi, bip, Wg, bgp, Wo,
                                           bop, ph, out, flags, hbuf);
}

// Round 15
// 2913.394 us; speedup vs baseline: 1.3315x; 1.0026x over previous
//
#include <hip/hip_runtime.h>

#define TT 1024
#define BB 64
#define DD 512
#define HH 512
#define NG 4       // batch groups (16 batches each)
#define BPG 16
#define NS 32      // hidden slices (16 units each)
#define NTHR 256

typedef short s8v __attribute__((ext_vector_type(8)));
typedef float f4v __attribute__((ext_vector_type(4)));
typedef int i4v __attribute__((ext_vector_type(4)));

// raw barrier: LDS visibility only (lgkm), does NOT drain vmcnt -> global
// loads stay in flight across it (unlike __syncthreads' vmcnt(0) drain).
#define LGKM_BAR()                                          \
  do {                                                      \
    asm volatile("s_waitcnt lgkmcnt(0)" ::: "memory");      \
    __builtin_amdgcn_sched_barrier(0);                      \
    __builtin_amdgcn_s_barrier();                           \
    __builtin_amdgcn_sched_barrier(0);                      \
  } while (0)

static __device__ __forceinline__ unsigned short f2bf(float f) {
  union { float f; unsigned int u; } v; v.f = f;
  unsigned int r = v.u + 0x7FFFu + ((v.u >> 16) & 1u);  // RNE
  return (unsigned short)(r >> 16);
}
static __device__ __forceinline__ i4v ld_b128_cohere(const void* p) {
  i4v r;
  asm volatile("global_load_dwordx4 %0, %1, off sc0 sc1"
               : "=v"(r) : "v"(p) : "memory");
  return r;
}
// async coherent flag load: NO embedded waitcnt (pipelined poll)
static __device__ __forceinline__ int ld_b32_cohere_async(const void* p) {
  int r;
  asm volatile("global_load_dword %0, %1, off sc0 sc1"
               : "=v"(r) : "v"(p) : "memory");
  return r;
}
static __device__ __forceinline__ void st_b32_cohere(void* p, unsigned int v) {
  asm volatile("global_store_dword %0, %1, off sc0 sc1"
               :: "v"(p), "v"(v) : "memory");
}
static __device__ __forceinline__ unsigned int cvtpk_bf16(float lo, float hi) {
  unsigned int r;
  asm("v_cvt_pk_bf16_f32 %0, %1, %2" : "=v"(r) : "v"(lo), "v"(hi));
  return r;
}

// Reset flags every launch (graph replays rerun this).
__global__ void __launch_bounds__(128, 1) qlstm_init(int* flags) {
  st_b32_cohere(flags + threadIdx.x, 0u);   // flags[NG][NS] = 128 ints
}

__global__ void __launch_bounds__(NTHR, 1) qlstm_main(
    const float* __restrict__ X,
    const float* __restrict__ Wf, const float* __restrict__ bfp,
    const float* __restrict__ Wi, const float* __restrict__ bip,
    const float* __restrict__ Wg, const float* __restrict__ bgp,
    const float* __restrict__ Wo, const float* __restrict__ bop,
    const float* __restrict__ phase,
    float* __restrict__ out, int* __restrict__ flags,
    unsigned short* __restrict__ hbuf) {
  __shared__ float zx[2][2][4][64][4];  // [par][khalf][tile][lane][i]
  __shared__ float zh[2][4][64][4];     // [khalf][tile][lane][i]
  const int tid   = threadIdx.x;
  const int wv    = tid >> 6;
  const int lane  = tid & 63;
  const int n     = lane & 15;
  const int kg    = lane >> 4;
  const int group = blockIdx.x & (NG - 1);
  const int slice = blockIdx.x >> 2;
  const int b0 = group * BPG;
  const int u0 = slice * 16;
  const bool isH = (wv >= 2);
  const int kh = wv & 1;   // K-half within role

  // Per-wave weights: 4 tiles x K=256 (layout identical to R9).
  const int wcol = u0 + (n & 7);
  s8v wreg[4][8];
#pragma unroll
  for (int T = 0; T < 4; ++T) {
    const float* Wsel = (T & 1) ? ((n < 8) ? Wg : Wo) : ((n < 8) ? Wf : Wi);
    const float* Wp = Wsel + (size_t)((isH ? 512 : 0) + kh * 256 + kg * 8) * HH
                    + wcol + (T >> 1) * 8;
#pragma unroll
    for (int kc = 0; kc < 8; ++kc)
#pragma unroll
      for (int j = 0; j < 8; ++j)
        wreg[T][kc][j] = (short)f2bf(Wp[(size_t)(kc * 32 + j) * HH]);
  }

  const int gb = tid >> 4, gu = tid & 15;
  const int uu = u0 + gu;
  const float bzf = bfp[uu] + phase[uu];
  const float bzi = bip[uu] + phase[uu];
  const float bzg = bgp[uu] + phase[uu];
  const float bzo = bop[uu] + phase[uu];
  float cst = 0.f;

  // prologue: zero zh (h(-1)=0); x-waves compute zx(0), issue LD(1)
  for (int p = tid; p < 2 * 4 * 64 * 4; p += NTHR) ((float*)zh)[p] = 0.f;
  float4 xv[16];
  s8v xf[8];
  if (!isH) {
    const float* Xr = X + ((size_t)0 * BB + b0 + n) * DD + kh * 256 + kg * 8;
#pragma unroll
    for (int kc = 0; kc < 8; ++kc) {
      xv[2 * kc]     = *(const float4*)(Xr + kc * 32);
      xv[2 * kc + 1] = *(const float4*)(Xr + kc * 32 + 4);
    }
#pragma unroll
    for (int kc = 0; kc < 8; ++kc) {
      union { s8v s; unsigned int d[4]; } af;
      af.d[0] = cvtpk_bf16(xv[2 * kc].x, xv[2 * kc].y);
      af.d[1] = cvtpk_bf16(xv[2 * kc].z, xv[2 * kc].w);
      af.d[2] = cvtpk_bf16(xv[2 * kc + 1].x, xv[2 * kc + 1].y);
      af.d[3] = cvtpk_bf16(xv[2 * kc + 1].z, xv[2 * kc + 1].w);
      xf[kc] = af.s;
    }
    f4v acc[4] = {{0.f,0.f,0.f,0.f},{0.f,0.f,0.f,0.f},{0.f,0.f,0.f,0.f},{0.f,0.f,0.f,0.f}};
#pragma unroll
    for (int kc = 0; kc < 8; ++kc)
#pragma unroll
      for (int T = 0; T < 4; ++T)
        acc[T] = __builtin_amdgcn_mfma_f32_16x16x32_bf16(xf[kc], wreg[T][kc], acc[T], 0, 0, 0);
#pragma unroll
    for (int T = 0; T < 4; ++T) *(f4v*)&zx[0][kh][T][lane][0] = acc[T];
    const float* X1 = X + ((size_t)1 * BB + b0 + n) * DD + kh * 256 + kg * 8;
#pragma unroll
    for (int kc = 0; kc < 8; ++kc) {
      xv[2 * kc]     = *(const float4*)(X1 + kc * 32);
      xv[2 * kc + 1] = *(const float4*)(X1 + kc * 32 + 4);
    }
  }

  int* myflag = flags + group * NS + slice;
  const int* pollp = flags + group * NS + (lane & 31);

  for (int t = 0; t < TT; ++t) {
    // ---------- P1: x-waves build zx(t+1); h-waves poll+load+MFMA zh(t) ----
    if (!isH) {
      if (t + 1 < TT) {
        // cvt xv (loads issued last step -> a full step of flight time)
#pragma unroll
        for (int kc = 0; kc < 8; ++kc) {
          union { s8v s; unsigned int d[4]; } af;
          af.d[0] = cvtpk_bf16(xv[2 * kc].x, xv[2 * kc].y);
          af.d[1] = cvtpk_bf16(xv[2 * kc].z, xv[2 * kc].w);
          af.d[2] = cvtpk_bf16(xv[2 * kc + 1].x, xv[2 * kc + 1].y);
          af.d[3] = cvtpk_bf16(xv[2 * kc + 1].z, xv[2 * kc + 1].w);
          xf[kc] = af.s;
        }
        f4v acc[4] = {{0.f,0.f,0.f,0.f},{0.f,0.f,0.f,0.f},{0.f,0.f,0.f,0.f},{0.f,0.f,0.f,0.f}};
#pragma unroll
        for (int kc = 0; kc < 8; ++kc)
#pragma unroll
          for (int T = 0; T < 4; ++T)
            acc[T] = __builtin_amdgcn_mfma_f32_16x16x32_bf16(xf[kc], wreg[T][kc], acc[T], 0, 0, 0);
#pragma unroll
        for (int T = 0; T < 4; ++T)
          *(f4v*)&zx[(t + 1) & 1][kh][T][lane][0] = acc[T];
      }
    } else if (t > 0) {
      // ---- pipelined 2-slot flag poll: check period ~100cy instead of a
      // full L3 RT. On success, the stale in-flight poll load is NOT drained
      // here — the h-load batch's vmcnt(0) below absorbs it for free. ----
      {
        int v0 = ld_b32_cohere_async(pollp);
        int v1 = ld_b32_cohere_async(pollp);
        for (;;) {
          asm volatile("s_waitcnt vmcnt(1)" ::: "memory");
          __builtin_amdgcn_sched_barrier(0);
          if (__all(v0 >= t)) break;
          v0 = ld_b32_cohere_async(pollp);
          asm volatile("s_waitcnt vmcnt(1)" ::: "memory");
          __builtin_amdgcn_sched_barrier(0);
          if (__all(v1 >= t)) break;
          v1 = ld_b32_cohere_async(pollp);
          __builtin_amdgcn_s_sleep(1);
        }
      }
      // h(t-1) direct global->A-frag: lane (row=b0+n, k=kh*256+kc*32+kg*8+j)
      const unsigned short* hb = hbuf + (size_t)((t - 1) & 1) * BB * HH +
                                 (size_t)(b0 + n) * HH + kh * 256 + kg * 8;
      i4v hf[8];
#pragma unroll
      for (int kc = 0; kc < 8; ++kc) hf[kc] = ld_b128_cohere(hb + kc * 32);
      asm volatile("s_waitcnt vmcnt(0)" ::: "memory");   // rule-18 fence
      __builtin_amdgcn_sched_barrier(0);
      f4v acc[4] = {{0.f,0.f,0.f,0.f},{0.f,0.f,0.f,0.f},{0.f,0.f,0.f,0.f},{0.f,0.f,0.f,0.f}};
#pragma unroll
      for (int kc = 0; kc < 8; ++kc) {
        union { i4v i; s8v s; } af; af.i = hf[kc];
#pragma unroll
        for (int T = 0; T < 4; ++T)
          acc[T] = __builtin_amdgcn_mfma_f32_16x16x32_bf16(af.s, wreg[T][kc], acc[T], 0, 0, 0);
      }
#pragma unroll
      for (int T = 0; T < 4; ++T) *(f4v*)&zh[kh][T][lane][0] = acc[T];
    }
    LGKM_BAR();                                         // bar1 (raw)

    // ---------- gates on ALL 256 threads (1 unit each; layout = R9) --------
    const int par = t & 1;
    const int Lf  = (gb >> 2) * 16 + (gu & 7);
    const int T0  = (gu >> 3) * 2;
    const int ci  = gb & 3;
    const float zfv = zx[par][0][T0][Lf][ci]     + zx[par][1][T0][Lf][ci]
                    + zh[0][T0][Lf][ci]          + zh[1][T0][Lf][ci] + bzf;
    const float ziv = zx[par][0][T0][Lf+8][ci]   + zx[par][1][T0][Lf+8][ci]
                    + zh[0][T0][Lf+8][ci]        + zh[1][T0][Lf+8][ci] + bzi;
    const float zgv = zx[par][0][T0+1][Lf][ci]   + zx[par][1][T0+1][Lf][ci]
                    + zh[0][T0+1][Lf][ci]        + zh[1][T0+1][Lf][ci] + bzg;
    const float zov = zx[par][0][T0+1][Lf+8][ci] + zx[par][1][T0+1][Lf+8][ci]
                    + zh[0][T0+1][Lf+8][ci]      + zh[1][T0+1][Lf+8][ci] + bzo;
    const float fg = 1.f / (1.f + __expf(-zfv));
    const float ig = 1.f / (1.f + __expf(-ziv));
    const float gg = 1.f - 2.f / (__expf(2.f * zgv) + 1.f);
    const float og = 1.f / (1.f + __expf(-zov));
    cst = fg * cst + ig * gg;
    const float hv = og * (1.f - 2.f / (__expf(2.f * cst) + 1.f));

    // ---------- publish h; x-waves then issue LD(t+2); counted drain -------
    const float hn = __shfl_down(hv, 1);
    if (!(gu & 1))
      st_b32_cohere(hbuf + (size_t)par * BB * HH + (size_t)(b0 + gb) * HH + uu,
                    cvtpk_bf16(hv, hn));                 // 1 store (oldest)
    if (!isH && t + 2 < TT) {
      const float* Xr = X + ((size_t)(t + 2) * BB + b0 + n) * DD + kh * 256 + kg * 8;
#pragma unroll
      for (int kc = 0; kc < 8; ++kc) {                   // 16 b128 loads
        xv[2 * kc]     = *(const float4*)(Xr + kc * 32);
        xv[2 * kc + 1] = *(const float4*)(Xr + kc * 32 + 4);
      }
      // wait for the publish store ONLY (oldest of 17): loads stay in flight
      asm volatile("s_waitcnt vmcnt(16)" ::: "memory");
    } else {
      asm volatile("s_waitcnt vmcnt(0)" ::: "memory");   // h-waves + tail
    }
    __builtin_amdgcn_sched_barrier(0);
    __builtin_amdgcn_s_barrier();   // ALL waves' publish stores acked (race fix)
    __builtin_amdgcn_sched_barrier(0);
    if (tid == 0) st_b32_cohere(myflag, (unsigned int)(t + 1));

    // out stores after flag; never drained by a barrier (acked next step)
    out[(size_t)t * BB * HH + (size_t)(b0 + gb) * HH + uu] = hv;
    if (t == TT - 1) {
      out[(size_t)TT * BB * HH + (size_t)(b0 + gb) * HH + uu] = hv;          // hx
      out[(size_t)TT * BB * HH + BB * HH + (size_t)(b0 + gb) * HH + uu] = cst; // cx
    }
    LGKM_BAR();                                         // bar2 (raw)
  }
}

extern "C" void kernel_launch(void* const* d_in, const int* in_sizes, int n_in,
                              void* d_out, int out_size, void* d_ws,
                              size_t ws_size, hipStream_t stream) {
  const float* X   = (const float*)d_in[0];
  const float* Wf  = (const float*)d_in[1];
  const float* bfp = (const float*)d_in[2];
  const float* Wi  = (const float*)d_in[3];
  const float* bip = (const float*)d_in[4];
  const float* Wg  = (const float*)d_in[5];
  const float* bgp = (const float*)d_in[6];
  const float* Wo  = (const float*)d_in[7];
  const float* bop = (const float*)d_in[8];
  const float* ph  = (const float*)d_in[9];
  float* out = (float*)d_out;

  // ws: [0, 512B) flags[NG][NS]; [4KB, 4KB+128KB) bf16 h double-buffer
  int* flags = (int*)d_ws;
  unsigned short* hbuf = (unsigned short*)((char*)d_ws + 4096);

  qlstm_init<<<1, 128, 0, stream>>>(flags);
  qlstm_main<<<NG * NS, NTHR, 0, stream>>>(X, Wf, bfp, Wi, bip, Wg, bgp, Wo,
                                           bop, ph, out, flags, hbuf);
}